// Round 1
// 572.117 us; speedup vs baseline: 1.1973x; 1.1973x over previous
//
#include <hip/hip_runtime.h>
#include <math.h>

#define Bb 8
#define Cc 64
#define Hh 256
#define Ww 256
#define HID 8
#define PLANE (Hh*Ww)

// ---------------- theta kernel: float2 channel-paired 3x3 conv -------------
// Block = 64x4 pixels. Tile per channel-pair: rows [y0-1,y0+4], cols
// [x0-1,x0+64] = 6 x 66 float2 (ch c in .x, ch c+1 in .y), zero-padded at
// image borders. Staging descriptors hoisted out of the channel loop; next
// pair's global loads issued before the conv so HBM latency hides under it.
#define T2H 6
#define T2W 66
#define T2P 67          // float2 row stride
#define T2N (T2H*T2W)   // 396

__global__ __launch_bounds__(256, 4) void theta_kernel(
    const float* __restrict__ x, const float* __restrict__ w3,
    const float* __restrict__ b3, const float* __restrict__ w1,
    const float* __restrict__ b1, float* __restrict__ cosout,
    float* __restrict__ sinout)
{
    __shared__ float2 tile[T2H * T2P];
    const int tid = threadIdx.x;
    const int tx = tid & 63;
    const int ty = tid >> 6;
    const int xx = blockIdx.x * 64 + tx;
    const int yy = blockIdx.y * 4 + ty;
    const int b  = blockIdx.z;
    const int row0 = blockIdx.y * 4 - 1;
    const int col0 = blockIdx.x * 64 - 1;

    const float* xb = x + (size_t)b * Cc * PLANE;

    // channel-invariant staging descriptors (2 positions per thread)
    int goff[2], loff[2];
    bool intile[2], inimg[2];
    #pragma unroll
    for (int k = 0; k < 2; k++) {
        const int i  = tid + k * 256;
        const int r  = i / T2W;
        const int cc = i - r * T2W;
        const int gy = row0 + r;
        const int gx = col0 + cc;
        intile[k] = (i < T2N);
        inimg[k]  = intile[k] && gy >= 0 && gy < Hh && gx >= 0 && gx < Ww;
        goff[k] = inimg[k] ? (gy * Ww + gx) : 0;
        loff[k] = r * T2P + cc;
    }

    float acc[HID];
    #pragma unroll
    for (int h = 0; h < HID; h++) acc[h] = 0.f;

    // prefetch pair 0 (out-of-image positions stay 0 forever -> zero pad)
    float rvx[2] = {0.f, 0.f}, rvy[2] = {0.f, 0.f};
    #pragma unroll
    for (int k = 0; k < 2; k++) if (inimg[k]) {
        rvx[k] = xb[goff[k]];
        rvy[k] = xb[goff[k] + PLANE];
    }

    const int lbase = (ty + 1) * T2P + (tx + 1);

    for (int cp = 0; cp < Cc / 2; cp++) {
        __syncthreads();                      // previous tile fully consumed
        #pragma unroll
        for (int k = 0; k < 2; k++)
            if (intile[k]) tile[loff[k]] = make_float2(rvx[k], rvy[k]);
        if (cp + 1 < Cc / 2) {                // issue next loads early
            const float* xn = xb + (size_t)(2 * (cp + 1)) * PLANE;
            #pragma unroll
            for (int k = 0; k < 2; k++) if (inimg[k]) {
                rvx[k] = xn[goff[k]];
                rvy[k] = xn[goff[k] + PLANE];
            }
        }
        __syncthreads();                      // tile ready

        float2 v[9];
        #pragma unroll
        for (int dy = 0; dy < 3; dy++)
            #pragma unroll
            for (int dx = 0; dx < 3; dx++)
                v[dy * 3 + dx] = tile[lbase + (dy - 1) * T2P + (dx - 1)];

        #pragma unroll
        for (int h = 0; h < HID; h++) {
            const float* wk = w3 + (size_t)(h * Cc + 2 * cp) * 9;  // uniform
            float a = acc[h];
            #pragma unroll
            for (int k = 0; k < 9; k++) a = fmaf(wk[k],     v[k].x, a);
            #pragma unroll
            for (int k = 0; k < 9; k++) a = fmaf(wk[9 + k], v[k].y, a);
            acc[h] = a;
        }
    }

    float z = b1[0];
    #pragma unroll
    for (int h = 0; h < HID; h++) {
        float hr = acc[h] + b3[h];
        hr = hr > 0.f ? hr : 0.f;
        z = fmaf(w1[h], hr, z);
    }
    const float theta = 3.14159265358979f / (1.f + __expf(-z));
    float s, co;
    __sincosf(theta, &s, &co);
    const int p = b * PLANE + yy * Ww + xx;
    cosout[p] = co;
    sinout[p] = s;
}

// ---------------- pool kernel: float2-paired oriented pooling + attention --
// Block = 64x4 pixels. Tile per channel-pair: rows [y0-4,y0+8] x cols
// [x0-4,x0+69] = 13 x 74 float2 (clamp-padded). 16 bilinear descriptors
// (t=0 excluded: it is exactly the center pixel for both directions) kept
// RESIDENT across the channel loop -- launch_bounds(256,3) gives the
// register budget so the backend does not rematerialize them per channel.
#define TPH 13
#define TPW 74
#define TPP 75          // float2 row stride
#define TPN (TPH*TPW)   // 962

__global__ __launch_bounds__(256, 3) void pool_kernel(
    const float* __restrict__ x,
    const float* __restrict__ cosb, const float* __restrict__ sinb,
    const float* __restrict__ wr, const float* __restrict__ br,
    const float* __restrict__ we, const float* __restrict__ be,
    float* __restrict__ out)
{
    __shared__ float2 tile[TPH * TPP];
    const int tid = threadIdx.x;
    const int tx = tid & 63;
    const int ty = tid >> 6;
    const int xx = blockIdx.x * 64 + tx;
    const int yy = blockIdx.y * 4 + ty;
    const int b  = blockIdx.z;
    const int p  = b * PLANE + yy * Ww + xx;
    const int row0 = blockIdx.y * 4 - 4;
    const int col0 = blockIdx.x * 64 - 4;

    const float vx = cosb[p];   // cos(theta)
    const float vy = sinb[p];   // sin(theta)

    // 16 bilinear descriptors (8 tan + 8 nor, t != 0), tile-local offsets.
    // Clamp trick: x0=min(floor(cx),W-2), wx=cx-x0 matches reference edges.
    int   off[16];
    float fwy[16], fwx[16];
    #pragma unroll
    for (int s = 0; s < 9; s++) {
        if (s == 4) continue;                 // t=0 handled as exact center
        const int j = (s < 4) ? s : s - 1;    // 0..7
        const float t = (float)(s - 4);
        float cy = fminf(fmaxf((float)yy + t * vy, 0.f), (float)(Hh - 1));
        float cx = fminf(fmaxf((float)xx + t * vx, 0.f), (float)(Ww - 1));
        int y0 = min((int)cy, Hh - 2);
        int x0 = min((int)cx, Ww - 2);
        off[j] = (y0 - row0) * TPP + (x0 - col0);
        fwy[j] = cy - (float)y0;
        fwx[j] = cx - (float)x0;
        float cy2 = fminf(fmaxf((float)yy + t * vx, 0.f), (float)(Hh - 1));
        float cx2 = fminf(fmaxf((float)xx - t * vy, 0.f), (float)(Ww - 1));
        int y02 = min((int)cy2, Hh - 2);
        int x02 = min((int)cx2, Ww - 2);
        off[8 + j] = (y02 - row0) * TPP + (x02 - col0);
        fwy[8 + j] = cy2 - (float)y02;
        fwx[8 + j] = cx2 - (float)x02;
    }
    const int lcen = (ty + 4) * TPP + (tx + 4);

    // channel-invariant staging descriptors (4 positions per thread;
    // tail threads duplicate the last element -- benign same-value write)
    int goff[4], loff[4];
    #pragma unroll
    for (int k = 0; k < 4; k++) {
        int i = tid + k * 256;
        i = (i < TPN) ? i : (TPN - 1);
        const int r  = i / TPW;
        const int cc = i - r * TPW;
        const int gy = min(max(row0 + r, 0), Hh - 1);
        const int gx = min(max(col0 + cc, 0), Ww - 1);
        goff[k] = gy * Ww + gx;
        loff[k] = r * TPP + cc;
    }

    float hid[HID];
    #pragma unroll
    for (int h = 0; h < HID; h++) hid[h] = br[h];

    const float* xb = x + (size_t)b * Cc * PLANE;

    // prefetch pair 0
    float rvx[4], rvy[4];
    #pragma unroll
    for (int k = 0; k < 4; k++) {
        rvx[k] = xb[goff[k]];
        rvy[k] = xb[goff[k] + PLANE];
    }

    for (int cp = 0; cp < Cc / 2; cp++) {
        __syncthreads();                      // previous tile fully sampled
        #pragma unroll
        for (int k = 0; k < 4; k++)
            tile[loff[k]] = make_float2(rvx[k], rvy[k]);
        if (cp + 1 < Cc / 2) {                // issue next loads early; their
            const float* xn = xb + (size_t)(2 * (cp + 1)) * PLANE;
            #pragma unroll                    // latency hides under sampling
            for (int k = 0; k < 4; k++) {
                rvx[k] = xn[goff[k]];
                rvy[k] = xn[goff[k] + PLANE];
            }
        }
        __syncthreads();                      // tile ready

        const float2 cent = tile[lcen];       // exact t=0 sample, both dirs
        float tacc0 = cent.x, tacc1 = cent.y;
        float nacc0 = cent.x, nacc1 = cent.y;
        #pragma unroll
        for (int s = 0; s < 16; s++) {
            const int o = off[s];
            const float2 a00 = tile[o];
            const float2 a01 = tile[o + 1];         // ds_read2_b64 with a00
            const float2 a10 = tile[o + TPP];
            const float2 a11 = tile[o + TPP + 1];   // ds_read2_b64 with a10
            const float wx_ = fwx[s], wy_ = fwy[s];
            const float t0  = a00.x + wx_ * (a01.x - a00.x);
            const float b0  = a10.x + wx_ * (a11.x - a10.x);
            const float v0  = t0 + wy_ * (b0 - t0);
            const float t1  = a00.y + wx_ * (a01.y - a00.y);
            const float b1v = a10.y + wx_ * (a11.y - a10.y);
            const float v1  = t1 + wy_ * (b1v - t1);
            if (s < 8) { tacc0 += v0; tacc1 += v1; }
            else       { nacc0 += v0; nacc1 += v1; }
        }
        tacc0 *= (1.f / 9.f); tacc1 *= (1.f / 9.f);
        nacc0 *= (1.f / 9.f); nacc1 *= (1.f / 9.f);
        const int c = 2 * cp;
        #pragma unroll
        for (int h = 0; h < HID; h++) {
            float a = hid[h];
            a = fmaf(wr[h * 128 + c],          tacc0, a);   // uniform s_load
            a = fmaf(wr[h * 128 + 64 + c],     nacc0, a);
            a = fmaf(wr[h * 128 + c + 1],      tacc1, a);
            a = fmaf(wr[h * 128 + 64 + c + 1], nacc1, a);
            hid[h] = a;
        }
    }

    #pragma unroll
    for (int h = 0; h < HID; h++) hid[h] = fmaxf(hid[h], 0.f);

    // Epilogue: w = sigmoid(we @ hidden + be); out = (w[c] + w[c+64]) * x[c]
    const int pix = yy * Ww + xx;
    for (int c = 0; c < Cc; c++) {
        float z1 = be[c];
        float z2 = be[c + 64];
        #pragma unroll
        for (int h = 0; h < HID; h++) {
            z1 = fmaf(we[c * 8 + h],        hid[h], z1);
            z2 = fmaf(we[(c + 64) * 8 + h], hid[h], z2);
        }
        const float a1 = 1.f / (1.f + __expf(-z1));
        const float a2 = 1.f / (1.f + __expf(-z2));
        const float xv = xb[c * PLANE + pix];
        out[(size_t)(b * Cc + c) * PLANE + pix] = (a1 + a2) * xv;
    }
}

extern "C" void kernel_launch(void* const* d_in, const int* in_sizes, int n_in,
                              void* d_out, int out_size, void* d_ws, size_t ws_size,
                              hipStream_t stream) {
    const float* x  = (const float*)d_in[0];
    const float* w3 = (const float*)d_in[1];
    const float* b3 = (const float*)d_in[2];
    const float* w1 = (const float*)d_in[3];
    const float* b1 = (const float*)d_in[4];
    const float* wr = (const float*)d_in[5];
    const float* br = (const float*)d_in[6];
    const float* we = (const float*)d_in[7];
    const float* be = (const float*)d_in[8];
    float* out = (float*)d_out;

    float* cosb = (float*)d_ws;                    // B*H*W floats
    float* sinb = cosb + (size_t)Bb * PLANE;       // B*H*W floats

    dim3 grid(Ww / 64, Hh / 4, Bb);
    dim3 block(256);
    theta_kernel<<<grid, block, 0, stream>>>(x, w3, b3, w1, b1, cosb, sinb);
    pool_kernel<<<grid, block, 0, stream>>>(x, cosb, sinb, wr, br, we, be, out);
}

// Round 2
// 530.602 us; speedup vs baseline: 1.2910x; 1.0782x over previous
//
#include <hip/hip_runtime.h>
#include <math.h>

#define Bb 8
#define Cc 64
#define Hh 256
#define Ww 256
#define HID 8
#define PLANE (Hh*Ww)

typedef float fvec4 __attribute__((ext_vector_type(4)));

// ---------------- theta kernel: 8-channel-per-stage 3x3 conv ---------------
// Block = 64x4 pixels. Per stage: two float4 tiles (ch c..c+3, c+4..c+7),
// rows [y0-1,y0+4], cols [x0-1,x0+64] = 6 x 66, zero-padded at borders.
// 8 stages, 16 barriers total. Compute per stage (~2300 cy of FMA) exceeds
// global-load latency (~900 cy), so the early-issued prefetch fully hides.
#define T2H 6
#define T2W 66
#define T2P 67          // float4 row stride
#define T2N (T2H*T2W)   // 396

__global__ __launch_bounds__(256, 4) void theta_kernel(
    const float* __restrict__ x, const float* __restrict__ w3,
    const float* __restrict__ b3, const float* __restrict__ w1,
    const float* __restrict__ b1, float* __restrict__ cosout,
    float* __restrict__ sinout)
{
    __shared__ fvec4 tileA[T2H * T2P];
    __shared__ fvec4 tileB[T2H * T2P];
    const int tid = threadIdx.x;
    const int tx = tid & 63;
    const int ty = tid >> 6;
    const int xx = blockIdx.x * 64 + tx;
    const int yy = blockIdx.y * 4 + ty;
    const int b  = blockIdx.z;
    const int row0 = blockIdx.y * 4 - 1;
    const int col0 = blockIdx.x * 64 - 1;

    const float* xb = x + (size_t)b * Cc * PLANE;

    // channel-invariant staging descriptors (2 positions per thread)
    int goff[2], loff[2];
    bool intile[2], inimg[2];
    #pragma unroll
    for (int k = 0; k < 2; k++) {
        const int i  = tid + k * 256;
        const int r  = i / T2W;
        const int cc = i - r * T2W;
        const int gy = row0 + r;
        const int gx = col0 + cc;
        intile[k] = (i < T2N);
        inimg[k]  = intile[k] && gy >= 0 && gy < Hh && gx >= 0 && gx < Ww;
        goff[k] = inimg[k] ? (gy * Ww + gx) : 0;
        loff[k] = r * T2P + cc;
    }

    float acc[HID];
    #pragma unroll
    for (int h = 0; h < HID; h++) acc[h] = 0.f;

    // prefetch stage 0 (8 channels); out-of-image lanes stay 0 (zero pad)
    float rv[2][8];
    #pragma unroll
    for (int k = 0; k < 2; k++)
        #pragma unroll
        for (int q = 0; q < 8; q++) rv[k][q] = 0.f;
    #pragma unroll
    for (int k = 0; k < 2; k++) if (inimg[k]) {
        #pragma unroll
        for (int q = 0; q < 8; q++) rv[k][q] = xb[goff[k] + (size_t)q * PLANE];
    }

    const int lbase = (ty + 1) * T2P + (tx + 1);

    for (int st = 0; st < Cc / 8; st++) {
        __syncthreads();                      // previous tiles fully consumed
        #pragma unroll
        for (int k = 0; k < 2; k++) if (intile[k]) {
            tileA[loff[k]] = (fvec4){rv[k][0], rv[k][1], rv[k][2], rv[k][3]};
            tileB[loff[k]] = (fvec4){rv[k][4], rv[k][5], rv[k][6], rv[k][7]};
        }
        if (st + 1 < Cc / 8) {                // issue next 8-channel loads
            const float* xn = xb + (size_t)(st + 1) * 8 * PLANE;
            #pragma unroll
            for (int k = 0; k < 2; k++) if (inimg[k]) {
                #pragma unroll
                for (int q = 0; q < 8; q++)
                    rv[k][q] = xn[goff[k] + (size_t)q * PLANE];
            }
        }
        __syncthreads();                      // tiles ready

        fvec4 va[9], vb[9];
        #pragma unroll
        for (int dy = 0; dy < 3; dy++)
            #pragma unroll
            for (int dx = 0; dx < 3; dx++) {
                va[dy * 3 + dx] = tileA[lbase + (dy - 1) * T2P + (dx - 1)];
                vb[dy * 3 + dx] = tileB[lbase + (dy - 1) * T2P + (dx - 1)];
            }

        #pragma unroll
        for (int h = 0; h < HID; h++) {
            const float* wk = w3 + (size_t)(h * Cc + st * 8) * 9;  // uniform
            float a = acc[h];
            #pragma unroll
            for (int c = 0; c < 4; c++)
                #pragma unroll
                for (int k = 0; k < 9; k++)
                    a = fmaf(wk[c * 9 + k], va[k][c], a);
            #pragma unroll
            for (int c = 0; c < 4; c++)
                #pragma unroll
                for (int k = 0; k < 9; k++)
                    a = fmaf(wk[(4 + c) * 9 + k], vb[k][c], a);
            acc[h] = a;
        }
    }

    float z = b1[0];
    #pragma unroll
    for (int h = 0; h < HID; h++) {
        float hr = acc[h] + b3[h];
        hr = hr > 0.f ? hr : 0.f;
        z = fmaf(w1[h], hr, z);
    }
    const float theta = 3.14159265358979f / (1.f + __expf(-z));
    float s, co;
    __sincosf(theta, &s, &co);
    const int p = b * PLANE + yy * Ww + xx;
    cosout[p] = co;
    sinout[p] = s;
}

// ---------------- pool kernel: float4-staged oriented pooling + attention --
// Block = 64x4 pixels. Per stage: float4 tile (4 channels), rows [y0-4,y0+8]
// x cols [x0-4,x0+69] = 13 x 74, clamp-padded. 16 stages. The 16 bilinear
// descriptors (t=0 excluded: exact center pixel) are computed once and
// LAUNDERED through empty asm so the backend cannot rematerialize them per
// stage (round-1 post-mortem: VGPR=56 < live set => remat, 100us of VALU).
#define TPH 13
#define TPW 74
#define TPP 75          // float4 row stride
#define TPN (TPH*TPW)   // 962

__global__ __launch_bounds__(256, 3) void pool_kernel(
    const float* __restrict__ x,
    const float* __restrict__ cosb, const float* __restrict__ sinb,
    const float* __restrict__ wr, const float* __restrict__ br,
    const float* __restrict__ we, const float* __restrict__ be,
    float* __restrict__ out)
{
    __shared__ fvec4 tile[TPH * TPP];
    const int tid = threadIdx.x;
    const int tx = tid & 63;
    const int ty = tid >> 6;
    const int xx = blockIdx.x * 64 + tx;
    const int yy = blockIdx.y * 4 + ty;
    const int b  = blockIdx.z;
    const int p  = b * PLANE + yy * Ww + xx;
    const int row0 = blockIdx.y * 4 - 4;
    const int col0 = blockIdx.x * 64 - 4;

    const float vx = cosb[p];   // cos(theta)
    const float vy = sinb[p];   // sin(theta)

    // 16 bilinear descriptors (8 tan + 8 nor, t != 0), tile-local offsets.
    // Clamp trick: x0=min(floor(cx),W-2), wx=cx-x0 matches reference edges.
    int   off[16];
    float fwy[16], fwx[16];
    #pragma unroll
    for (int s = 0; s < 9; s++) {
        if (s == 4) continue;                 // t=0 handled as exact center
        const int j = (s < 4) ? s : s - 1;    // 0..7
        const float t = (float)(s - 4);
        float cy = fminf(fmaxf((float)yy + t * vy, 0.f), (float)(Hh - 1));
        float cx = fminf(fmaxf((float)xx + t * vx, 0.f), (float)(Ww - 1));
        int y0 = min((int)cy, Hh - 2);
        int x0 = min((int)cx, Ww - 2);
        off[j] = (y0 - row0) * TPP + (x0 - col0);
        fwy[j] = cy - (float)y0;
        fwx[j] = cx - (float)x0;
        float cy2 = fminf(fmaxf((float)yy + t * vx, 0.f), (float)(Hh - 1));
        float cx2 = fminf(fmaxf((float)xx - t * vy, 0.f), (float)(Ww - 1));
        int y02 = min((int)cy2, Hh - 2);
        int x02 = min((int)cx2, Ww - 2);
        off[8 + j] = (y02 - row0) * TPP + (x02 - col0);
        fwy[8 + j] = cy2 - (float)y02;
        fwx[8 + j] = cx2 - (float)x02;
    }
    // Force residency: opaque defs cannot be rematerialized by the backend.
    #pragma unroll
    for (int s = 0; s < 16; s++)
        asm volatile("" : "+v"(off[s]), "+v"(fwx[s]), "+v"(fwy[s]));

    const int lcen = (ty + 4) * TPP + (tx + 4);

    // channel-invariant staging descriptors (4 positions per thread;
    // tail threads duplicate the last element -- benign same-value write)
    int goff[4], loff[4];
    #pragma unroll
    for (int k = 0; k < 4; k++) {
        int i = tid + k * 256;
        i = (i < TPN) ? i : (TPN - 1);
        const int r  = i / TPW;
        const int cc = i - r * TPW;
        const int gy = min(max(row0 + r, 0), Hh - 1);
        const int gx = min(max(col0 + cc, 0), Ww - 1);
        goff[k] = gy * Ww + gx;
        loff[k] = r * TPP + cc;
    }
    #pragma unroll
    for (int k = 0; k < 4; k++)
        asm volatile("" : "+v"(goff[k]), "+v"(loff[k]));

    float hid[HID];
    #pragma unroll
    for (int h = 0; h < HID; h++) hid[h] = br[h];

    const float* xb = x + (size_t)b * Cc * PLANE;

    // prefetch stage 0 (4 channels per position)
    float rv[4][4];
    #pragma unroll
    for (int k = 0; k < 4; k++)
        #pragma unroll
        for (int q = 0; q < 4; q++)
            rv[k][q] = xb[goff[k] + (size_t)q * PLANE];

    for (int cp = 0; cp < Cc / 4; cp++) {
        __syncthreads();                      // previous tile fully sampled
        #pragma unroll
        for (int k = 0; k < 4; k++)
            tile[loff[k]] = (fvec4){rv[k][0], rv[k][1], rv[k][2], rv[k][3]};
        if (cp + 1 < Cc / 4) {                // issue next loads early; their
            const float* xn = xb + (size_t)(cp + 1) * 4 * PLANE;
            #pragma unroll                    // latency hides under sampling
            for (int k = 0; k < 4; k++)
                #pragma unroll
                for (int q = 0; q < 4; q++)
                    rv[k][q] = xn[goff[k] + (size_t)q * PLANE];
        }
        __syncthreads();                      // tile ready

        const fvec4 cent = tile[lcen];        // exact t=0 sample, both dirs
        float tac[4], nac[4];
        #pragma unroll
        for (int q = 0; q < 4; q++) { tac[q] = cent[q]; nac[q] = cent[q]; }

        #pragma unroll
        for (int s = 0; s < 16; s++) {
            const int o = off[s];
            const fvec4 a00 = tile[o];
            const fvec4 a01 = tile[o + 1];
            const fvec4 a10 = tile[o + TPP];
            const fvec4 a11 = tile[o + TPP + 1];
            const float wx_ = fwx[s], wy_ = fwy[s];
            #pragma unroll
            for (int q = 0; q < 4; q++) {
                const float tq = a00[q] + wx_ * (a01[q] - a00[q]);
                const float bq = a10[q] + wx_ * (a11[q] - a10[q]);
                const float vq = tq + wy_ * (bq - tq);
                if (s < 8) tac[q] += vq; else nac[q] += vq;
            }
        }
        const int c = 4 * cp;
        #pragma unroll
        for (int q = 0; q < 4; q++) {
            const float tq = tac[q] * (1.f / 9.f);
            const float nq = nac[q] * (1.f / 9.f);
            #pragma unroll
            for (int h = 0; h < HID; h++) {
                float a = hid[h];
                a = fmaf(wr[h * 128 + c + q],      tq, a);   // uniform s_load
                a = fmaf(wr[h * 128 + 64 + c + q], nq, a);
                hid[h] = a;
            }
        }
    }

    #pragma unroll
    for (int h = 0; h < HID; h++) hid[h] = fmaxf(hid[h], 0.f);

    // Epilogue: w = sigmoid(we @ hidden + be); out = (w[c] + w[c+64]) * x[c]
    const int pix = yy * Ww + xx;
    for (int c = 0; c < Cc; c++) {
        float z1 = be[c];
        float z2 = be[c + 64];
        #pragma unroll
        for (int h = 0; h < HID; h++) {
            z1 = fmaf(we[c * 8 + h],        hid[h], z1);
            z2 = fmaf(we[(c + 64) * 8 + h], hid[h], z2);
        }
        const float a1 = 1.f / (1.f + __expf(-z1));
        const float a2 = 1.f / (1.f + __expf(-z2));
        const float xv = xb[c * PLANE + pix];
        out[(size_t)(b * Cc + c) * PLANE + pix] = (a1 + a2) * xv;
    }
}

extern "C" void kernel_launch(void* const* d_in, const int* in_sizes, int n_in,
                              void* d_out, int out_size, void* d_ws, size_t ws_size,
                              hipStream_t stream) {
    const float* x  = (const float*)d_in[0];
    const float* w3 = (const float*)d_in[1];
    const float* b3 = (const float*)d_in[2];
    const float* w1 = (const float*)d_in[3];
    const float* b1 = (const float*)d_in[4];
    const float* wr = (const float*)d_in[5];
    const float* br = (const float*)d_in[6];
    const float* we = (const float*)d_in[7];
    const float* be = (const float*)d_in[8];
    float* out = (float*)d_out;

    float* cosb = (float*)d_ws;                    // B*H*W floats
    float* sinb = cosb + (size_t)Bb * PLANE;       // B*H*W floats

    dim3 grid(Ww / 64, Hh / 4, Bb);
    dim3 block(256);
    theta_kernel<<<grid, block, 0, stream>>>(x, w3, b3, w1, b1, cosb, sinb);
    pool_kernel<<<grid, block, 0, stream>>>(x, cosb, sinb, wr, br, we, be, out);
}

// Round 3
// 527.816 us; speedup vs baseline: 1.2978x; 1.0053x over previous
//
#include <hip/hip_runtime.h>
#include <math.h>

#define Bb 8
#define Cc 64
#define Hh 256
#define Ww 256
#define HID 8
#define PLANE (Hh*Ww)

typedef float fvec4 __attribute__((ext_vector_type(4)));

// ===== Fused kernel: theta (3x3 conv -> 1x1 -> sigmoid*pi) + oriented =====
// pooling + attention, one dispatch.
//
// Rationale (round-2 post-mortem): the standalone theta kernel was stuck at
// ~260-280us across three structurally different versions while containing
// only ~30us of FMA + 20us of HBM traffic. Its 3x3 halo is a strict subset
// of the pool tile, and theta(p) feeds only pixel p -- so we fold it into
// the pool kernel as a first channel-pass over the same LDS tiles and
// delete the dispatch + cos/sin workspace round-trip entirely.
//
// Block = 64x4 pixels. Per stage: float4 tile (4 channels), rows
// [y0-4,y0+8] x cols [x0-4,x0+69] = 13 x 74, clamp-padded. 16 stages per
// pass, two passes (conv, pool). Zero-padding for the conv is recovered
// from the clamp-padded tile by multiplying out-of-image taps by 0
// (edge blocks only; block-uniform branch).
#define TPH 13
#define TPW 74
#define TPP 75          // float4 row stride
#define TPN (TPH*TPW)   // 962

__global__ __launch_bounds__(256, 3) void fused_kernel(
    const float* __restrict__ x,
    const float* __restrict__ w3, const float* __restrict__ b3,
    const float* __restrict__ w1, const float* __restrict__ b1,
    const float* __restrict__ wr, const float* __restrict__ br,
    const float* __restrict__ we, const float* __restrict__ be,
    float* __restrict__ out)
{
    __shared__ fvec4 tile[TPH * TPP];
    const int tid = threadIdx.x;
    const int tx = tid & 63;
    const int ty = tid >> 6;
    const int xx = blockIdx.x * 64 + tx;
    const int yy = blockIdx.y * 4 + ty;
    const int b  = blockIdx.z;
    const int row0 = blockIdx.y * 4 - 4;
    const int col0 = blockIdx.x * 64 - 4;

    // channel-invariant staging descriptors (4 positions per thread;
    // tail threads duplicate the last element -- benign same-value write)
    int goff[4], loff[4];
    #pragma unroll
    for (int k = 0; k < 4; k++) {
        int i = tid + k * 256;
        i = (i < TPN) ? i : (TPN - 1);
        const int r  = i / TPW;
        const int cc = i - r * TPW;
        const int gy = min(max(row0 + r, 0), Hh - 1);
        const int gx = min(max(col0 + cc, 0), Ww - 1);
        goff[k] = gy * Ww + gx;
        loff[k] = r * TPP + cc;
    }
    #pragma unroll
    for (int k = 0; k < 4; k++)
        asm volatile("" : "+v"(goff[k]), "+v"(loff[k]));

    const int lcen = (ty + 4) * TPP + (tx + 4);
    const float* xb = x + (size_t)b * Cc * PLANE;

    // ---- conv border masks (block-uniform interior fast path) ----
    const bool interior = (blockIdx.y > 0) && (blockIdx.y < (Hh/4 - 1)) &&
                          (blockIdx.x > 0) && (blockIdx.x < (Ww/64 - 1));
    float mk[9];
    #pragma unroll
    for (int dy = 0; dy < 3; dy++)
        #pragma unroll
        for (int dx = 0; dx < 3; dx++) {
            const int gy = yy + dy - 1, gx = xx + dx - 1;
            mk[dy*3+dx] = (gy >= 0 && gy < Hh && gx >= 0 && gx < Ww) ? 1.f : 0.f;
        }

    // ---- prefetch stage 0 (4 channels per position) ----
    float rv[4][4];
    #pragma unroll
    for (int k = 0; k < 4; k++)
        #pragma unroll
        for (int q = 0; q < 4; q++)
            rv[k][q] = xb[goff[k] + (size_t)q * PLANE];

    // ================= pass 1: 3x3 conv accumulation =================
    float acc[HID];
    #pragma unroll
    for (int h = 0; h < HID; h++) acc[h] = 0.f;

    for (int st = 0; st < Cc / 4; st++) {
        __syncthreads();                      // previous tile fully consumed
        #pragma unroll
        for (int k = 0; k < 4; k++)
            tile[loff[k]] = (fvec4){rv[k][0], rv[k][1], rv[k][2], rv[k][3]};
        {   // prefetch next stage; at st==15 prefetch pass-2 stage 0 (ch 0-3)
            const int nst = (st + 1 < Cc / 4) ? st + 1 : 0;
            const float* xn = xb + (size_t)nst * 4 * PLANE;
            #pragma unroll
            for (int k = 0; k < 4; k++)
                #pragma unroll
                for (int q = 0; q < 4; q++)
                    rv[k][q] = xn[goff[k] + (size_t)q * PLANE];
        }
        __syncthreads();                      // tile ready

        fvec4 va[9];
        #pragma unroll
        for (int dy = 0; dy < 3; dy++)
            #pragma unroll
            for (int dx = 0; dx < 3; dx++)
                va[dy*3+dx] = tile[lcen + (dy - 1) * TPP + (dx - 1)];
        if (!interior) {                      // zero-pad: clamp-tile * mask
            #pragma unroll
            for (int k = 0; k < 9; k++) va[k] *= mk[k];
        }
        #pragma unroll
        for (int h = 0; h < HID; h++) {
            const float* wk = w3 + (size_t)(h * Cc + st * 4) * 9;  // uniform
            float a = acc[h];
            #pragma unroll
            for (int q = 0; q < 4; q++)
                #pragma unroll
                for (int k = 0; k < 9; k++)
                    a = fmaf(wk[q * 9 + k], va[k][q], a);
            acc[h] = a;
        }
    }

    // ================= theta -> bilinear descriptors =================
    float z = b1[0];
    #pragma unroll
    for (int h = 0; h < HID; h++) {
        float hr = acc[h] + b3[h];
        hr = hr > 0.f ? hr : 0.f;
        z = fmaf(w1[h], hr, z);
    }
    const float theta = 3.14159265358979f / (1.f + __expf(-z));
    float vy, vx;
    __sincosf(theta, &vy, &vx);               // vy=sin, vx=cos

    // 16 samples (8 tan + 8 nor, t != 0; t=0 is exactly the center pixel).
    // Clamp trick: x0=min(floor(cx),W-2), wx=cx-x0 matches reference edges.
    // Store 4 corner weights per sample -> pure 4-FMA accumulation later.
    int   off[16];
    float cw00[16], cw01[16], cw10[16], cw11[16];
    #pragma unroll
    for (int s = 0; s < 9; s++) {
        if (s == 4) continue;
        const int j = (s < 4) ? s : s - 1;    // 0..7
        const float t = (float)(s - 4);
        {   // tangential: cy = y + t*sin, cx = x + t*cos
            float cy = fminf(fmaxf((float)yy + t * vy, 0.f), (float)(Hh - 1));
            float cx = fminf(fmaxf((float)xx + t * vx, 0.f), (float)(Ww - 1));
            int y0 = min((int)cy, Hh - 2);
            int x0 = min((int)cx, Ww - 2);
            off[j] = (y0 - row0) * TPP + (x0 - col0);
            const float wy = cy - (float)y0, wx = cx - (float)x0;
            cw00[j] = (1.f - wy) * (1.f - wx);
            cw01[j] = (1.f - wy) * wx;
            cw10[j] = wy * (1.f - wx);
            cw11[j] = wy * wx;
        }
        {   // normal: cy = y + t*cos, cx = x - t*sin
            float cy = fminf(fmaxf((float)yy + t * vx, 0.f), (float)(Hh - 1));
            float cx = fminf(fmaxf((float)xx - t * vy, 0.f), (float)(Ww - 1));
            int y0 = min((int)cy, Hh - 2);
            int x0 = min((int)cx, Ww - 2);
            off[8 + j] = (y0 - row0) * TPP + (x0 - col0);
            const float wy = cy - (float)y0, wx = cx - (float)x0;
            cw00[8 + j] = (1.f - wy) * (1.f - wx);
            cw01[8 + j] = (1.f - wy) * wx;
            cw10[8 + j] = wy * (1.f - wx);
            cw11[8 + j] = wy * wx;
        }
    }
    // Force residency: opaque defs cannot be rematerialized per stage.
    #pragma unroll
    for (int s = 0; s < 16; s++) {
        asm volatile("" : "+v"(off[s]), "+v"(cw00[s]), "+v"(cw01[s]));
        asm volatile("" : "+v"(cw10[s]), "+v"(cw11[s]));
    }

    // ================= pass 2: oriented pooling =================
    float hid[HID];
    #pragma unroll
    for (int h = 0; h < HID; h++) hid[h] = br[h];

    for (int cp = 0; cp < Cc / 4; cp++) {
        __syncthreads();                      // previous tile fully sampled
        #pragma unroll
        for (int k = 0; k < 4; k++)
            tile[loff[k]] = (fvec4){rv[k][0], rv[k][1], rv[k][2], rv[k][3]};
        if (cp + 1 < Cc / 4) {                // issue next loads early; their
            const float* xn = xb + (size_t)(cp + 1) * 4 * PLANE;
            #pragma unroll                    // latency hides under sampling
            for (int k = 0; k < 4; k++)
                #pragma unroll
                for (int q = 0; q < 4; q++)
                    rv[k][q] = xn[goff[k] + (size_t)q * PLANE];
        }
        __syncthreads();                      // tile ready

        const fvec4 cent = tile[lcen];        // exact t=0 sample, both dirs
        float tac[4], nac[4];
        #pragma unroll
        for (int q = 0; q < 4; q++) { tac[q] = cent[q]; nac[q] = cent[q]; }

        #pragma unroll
        for (int s = 0; s < 16; s++) {
            const int o = off[s];
            const fvec4 a00 = tile[o];
            const fvec4 a01 = tile[o + 1];
            const fvec4 a10 = tile[o + TPP];
            const fvec4 a11 = tile[o + TPP + 1];
            const float u00 = cw00[s], u01 = cw01[s];
            const float u10 = cw10[s], u11 = cw11[s];
            #pragma unroll
            for (int q = 0; q < 4; q++) {
                float a = (s < 8) ? tac[q] : nac[q];
                a = fmaf(a00[q], u00, a);
                a = fmaf(a01[q], u01, a);
                a = fmaf(a10[q], u10, a);
                a = fmaf(a11[q], u11, a);
                if (s < 8) tac[q] = a; else nac[q] = a;
            }
        }
        const int c = 4 * cp;
        #pragma unroll
        for (int q = 0; q < 4; q++) {
            const float tq = tac[q] * (1.f / 9.f);
            const float nq = nac[q] * (1.f / 9.f);
            #pragma unroll
            for (int h = 0; h < HID; h++) {
                float a = hid[h];
                a = fmaf(wr[h * 128 + c + q],      tq, a);   // uniform s_load
                a = fmaf(wr[h * 128 + 64 + c + q], nq, a);
                hid[h] = a;
            }
        }
    }

    #pragma unroll
    for (int h = 0; h < HID; h++) hid[h] = fmaxf(hid[h], 0.f);

    // Epilogue: w = sigmoid(we @ hidden + be); out = (w[c] + w[c+64]) * x[c]
    const int pix = yy * Ww + xx;
    for (int c = 0; c < Cc; c++) {
        float z1 = be[c];
        float z2 = be[c + 64];
        #pragma unroll
        for (int h = 0; h < HID; h++) {
            z1 = fmaf(we[c * 8 + h],        hid[h], z1);
            z2 = fmaf(we[(c + 64) * 8 + h], hid[h], z2);
        }
        const float a1 = 1.f / (1.f + __expf(-z1));
        const float a2 = 1.f / (1.f + __expf(-z2));
        const float xv = xb[c * PLANE + pix];
        out[(size_t)(b * Cc + c) * PLANE + pix] = (a1 + a2) * xv;
    }
}

extern "C" void kernel_launch(void* const* d_in, const int* in_sizes, int n_in,
                              void* d_out, int out_size, void* d_ws, size_t ws_size,
                              hipStream_t stream) {
    const float* x  = (const float*)d_in[0];
    const float* w3 = (const float*)d_in[1];
    const float* b3 = (const float*)d_in[2];
    const float* w1 = (const float*)d_in[3];
    const float* b1 = (const float*)d_in[4];
    const float* wr = (const float*)d_in[5];
    const float* br = (const float*)d_in[6];
    const float* we = (const float*)d_in[7];
    const float* be = (const float*)d_in[8];
    float* out = (float*)d_out;

    dim3 grid(Ww / 64, Hh / 4, Bb);
    dim3 block(256);
    fused_kernel<<<grid, block, 0, stream>>>(x, w3, b3, w1, b1,
                                             wr, br, we, be, out);
}

// Round 4
// 499.223 us; speedup vs baseline: 1.3721x; 1.0573x over previous
//
#include <hip/hip_runtime.h>
#include <math.h>

#define Bb 8
#define Cc 64
#define Hh 256
#define Ww 256
#define HID 8
#define PLANE (Hh*Ww)

// packed half2 for LDS tiles (pass-2 is LDS-datapath-bound: 1 KB/lane/stage
// of corner reads at f32 ~= 280-330us of LDS pipe in a 386us kernel).
typedef _Float16 f16x2 __attribute__((ext_vector_type(2)));

static __device__ __forceinline__ f16x2 u2h(unsigned int u) {
    return __builtin_bit_cast(f16x2, u);
}
static __device__ __forceinline__ unsigned int h2u(f16x2 h) {
    return __builtin_bit_cast(unsigned int, h);
}

// ===== Fused kernel: theta (3x3 conv -> 1x1 -> sigmoid*pi) + oriented =====
// pooling + attention, one dispatch. Tiles stored as 4 channels packed into
// uint2 (2x half2). Bilinear runs in packed fp16 (v_pk_fma_f16); each
// sample's RESULT is converted to f32 and accumulated in f32, so only
// per-sample values carry fp16 rounding (~5e-3 worst), pooled feature error
// ~6e-4, output delta ~1e-3. The theta conv accumulates in f32 (fp16
// accumulation there would shift theta ~0.01 rad -> too much).
#define TPH 13
#define TPW 74
#define TPP 75          // uint2 row stride
#define TPN (TPH*TPW)   // 962

__global__ __launch_bounds__(256, 4) void fused_kernel(
    const float* __restrict__ x,
    const float* __restrict__ w3, const float* __restrict__ b3,
    const float* __restrict__ w1, const float* __restrict__ b1,
    const float* __restrict__ wr, const float* __restrict__ br,
    const float* __restrict__ we, const float* __restrict__ be,
    float* __restrict__ out)
{
    __shared__ uint2 tile[TPH * TPP];
    const int tid = threadIdx.x;
    const int tx = tid & 63;
    const int ty = tid >> 6;
    const int xx = blockIdx.x * 64 + tx;
    const int yy = blockIdx.y * 4 + ty;
    const int b  = blockIdx.z;
    const int row0 = blockIdx.y * 4 - 4;
    const int col0 = blockIdx.x * 64 - 4;

    // channel-invariant staging descriptors (4 positions per thread;
    // tail threads duplicate the last element -- benign same-value write)
    int goff[4], loff[4];
    #pragma unroll
    for (int k = 0; k < 4; k++) {
        int i = tid + k * 256;
        i = (i < TPN) ? i : (TPN - 1);
        const int r  = i / TPW;
        const int cc = i - r * TPW;
        const int gy = min(max(row0 + r, 0), Hh - 1);
        const int gx = min(max(col0 + cc, 0), Ww - 1);
        goff[k] = gy * Ww + gx;
        loff[k] = r * TPP + cc;
    }
    #pragma unroll
    for (int k = 0; k < 4; k++)
        asm volatile("" : "+v"(goff[k]), "+v"(loff[k]));

    const int lcen = (ty + 4) * TPP + (tx + 4);
    const float* xb = x + (size_t)b * Cc * PLANE;

    // ---- conv border masks (block-uniform interior fast path) ----
    const bool interior = (blockIdx.y > 0) && (blockIdx.y < (Hh/4 - 1)) &&
                          (blockIdx.x > 0) && (blockIdx.x < (Ww/64 - 1));
    float mk[9];
    #pragma unroll
    for (int dy = 0; dy < 3; dy++)
        #pragma unroll
        for (int dx = 0; dx < 3; dx++) {
            const int gy = yy + dy - 1, gx = xx + dx - 1;
            mk[dy*3+dx] = (gy >= 0 && gy < Hh && gx >= 0 && gx < Ww) ? 1.f : 0.f;
        }

    // ---- prefetch stage 0 (4 channels per position, f32 from global) ----
    float rv[4][4];
    #pragma unroll
    for (int k = 0; k < 4; k++)
        #pragma unroll
        for (int q = 0; q < 4; q++)
            rv[k][q] = xb[goff[k] + (size_t)q * PLANE];

    // ================= pass 1: 3x3 conv accumulation (f32) =================
    float acc[HID];
    #pragma unroll
    for (int h = 0; h < HID; h++) acc[h] = 0.f;

    for (int st = 0; st < Cc / 4; st++) {
        __syncthreads();                      // previous tile fully consumed
        #pragma unroll
        for (int k = 0; k < 4; k++)
            tile[loff[k]] = make_uint2(
                h2u((f16x2){(_Float16)rv[k][0], (_Float16)rv[k][1]}),
                h2u((f16x2){(_Float16)rv[k][2], (_Float16)rv[k][3]}));
        {   // prefetch next stage; at st==15 prefetch pass-2 stage 0 (ch 0-3)
            const int nst = (st + 1 < Cc / 4) ? st + 1 : 0;
            const float* xn = xb + (size_t)nst * 4 * PLANE;
            #pragma unroll
            for (int k = 0; k < 4; k++)
                #pragma unroll
                for (int q = 0; q < 4; q++)
                    rv[k][q] = xn[goff[k] + (size_t)q * PLANE];
        }
        __syncthreads();                      // tile ready

        float va[9][4];
        #pragma unroll
        for (int dy = 0; dy < 3; dy++)
            #pragma unroll
            for (int dx = 0; dx < 3; dx++) {
                const uint2 cv = tile[lcen + (dy - 1) * TPP + (dx - 1)];
                const f16x2 lo = u2h(cv.x), hi = u2h(cv.y);
                const int k = dy * 3 + dx;
                va[k][0] = (float)lo.x; va[k][1] = (float)lo.y;
                va[k][2] = (float)hi.x; va[k][3] = (float)hi.y;
            }
        if (!interior) {                      // zero-pad: clamp-tile * mask
            #pragma unroll
            for (int k = 0; k < 9; k++)
                #pragma unroll
                for (int q = 0; q < 4; q++) va[k][q] *= mk[k];
        }
        #pragma unroll
        for (int h = 0; h < HID; h++) {
            const float* wk = w3 + (size_t)(h * Cc + st * 4) * 9;  // uniform
            float a = acc[h];
            #pragma unroll
            for (int q = 0; q < 4; q++)
                #pragma unroll
                for (int k = 0; k < 9; k++)
                    a = fmaf(wk[q * 9 + k], va[k][q], a);
            acc[h] = a;
        }
    }

    // ================= theta -> bilinear descriptors =================
    float z = b1[0];
    #pragma unroll
    for (int h = 0; h < HID; h++) {
        float hr = acc[h] + b3[h];
        hr = hr > 0.f ? hr : 0.f;
        z = fmaf(w1[h], hr, z);
    }
    const float theta = 3.14159265358979f / (1.f + __expf(-z));
    float vy, vx;
    __sincosf(theta, &vy, &vx);               // vy=sin, vx=cos

    // 16 samples (8 tan + 8 nor, t != 0; t=0 is exactly the center pixel).
    // Clamp trick: x0=min(floor(cx),W-2), wx=cx-x0 matches reference edges.
    // Lerp weights stored as broadcast half2 for packed-fp16 bilinear.
    int off[16];
    unsigned int wxp[16], wyp[16];
    #pragma unroll
    for (int s = 0; s < 9; s++) {
        if (s == 4) continue;
        const int j = (s < 4) ? s : s - 1;    // 0..7
        const float t = (float)(s - 4);
        {   // tangential: cy = y + t*sin, cx = x + t*cos
            float cy = fminf(fmaxf((float)yy + t * vy, 0.f), (float)(Hh - 1));
            float cx = fminf(fmaxf((float)xx + t * vx, 0.f), (float)(Ww - 1));
            int y0 = min((int)cy, Hh - 2);
            int x0 = min((int)cx, Ww - 2);
            off[j] = (y0 - row0) * TPP + (x0 - col0);
            const float wy = cy - (float)y0, wxx = cx - (float)x0;
            wxp[j] = h2u((f16x2){(_Float16)wxx, (_Float16)wxx});
            wyp[j] = h2u((f16x2){(_Float16)wy,  (_Float16)wy});
        }
        {   // normal: cy = y + t*cos, cx = x - t*sin
            float cy = fminf(fmaxf((float)yy + t * vx, 0.f), (float)(Hh - 1));
            float cx = fminf(fmaxf((float)xx - t * vy, 0.f), (float)(Ww - 1));
            int y0 = min((int)cy, Hh - 2);
            int x0 = min((int)cx, Ww - 2);
            off[8 + j] = (y0 - row0) * TPP + (x0 - col0);
            const float wy = cy - (float)y0, wxx = cx - (float)x0;
            wxp[8 + j] = h2u((f16x2){(_Float16)wxx, (_Float16)wxx});
            wyp[8 + j] = h2u((f16x2){(_Float16)wy,  (_Float16)wy});
        }
    }
    // Force residency: opaque defs cannot be rematerialized per stage.
    #pragma unroll
    for (int s = 0; s < 16; s++)
        asm volatile("" : "+v"(off[s]), "+v"(wxp[s]), "+v"(wyp[s]));

    // ================= pass 2: oriented pooling =================
    float hid[HID];
    #pragma unroll
    for (int h = 0; h < HID; h++) hid[h] = br[h];

    for (int cp = 0; cp < Cc / 4; cp++) {
        __syncthreads();                      // previous tile fully sampled
        #pragma unroll
        for (int k = 0; k < 4; k++)
            tile[loff[k]] = make_uint2(
                h2u((f16x2){(_Float16)rv[k][0], (_Float16)rv[k][1]}),
                h2u((f16x2){(_Float16)rv[k][2], (_Float16)rv[k][3]}));
        if (cp + 1 < Cc / 4) {                // issue next loads early; their
            const float* xn = xb + (size_t)(cp + 1) * 4 * PLANE;
            #pragma unroll                    // latency hides under sampling
            for (int k = 0; k < 4; k++)
                #pragma unroll
                for (int q = 0; q < 4; q++)
                    rv[k][q] = xn[goff[k] + (size_t)q * PLANE];
        }
        __syncthreads();                      // tile ready

        const uint2 cc = tile[lcen];          // exact t=0 sample, both dirs
        const f16x2 clo = u2h(cc.x), chi = u2h(cc.y);
        float tac[4], nac[4];
        tac[0] = nac[0] = (float)clo.x;
        tac[1] = nac[1] = (float)clo.y;
        tac[2] = nac[2] = (float)chi.x;
        tac[3] = nac[3] = (float)chi.y;

        #pragma unroll
        for (int s = 0; s < 16; s++) {
            const int o = off[s];
            const uint2 c00 = tile[o];
            const uint2 c01 = tile[o + 1];        // ds_read2_b64 with c00
            const uint2 c10 = tile[o + TPP];
            const uint2 c11 = tile[o + TPP + 1];  // ds_read2_b64 with c10
            const f16x2 wxh = u2h(wxp[s]);
            const f16x2 wyh = u2h(wyp[s]);
            const f16x2 a00 = u2h(c00.x), a01 = u2h(c01.x);
            const f16x2 a10 = u2h(c10.x), a11 = u2h(c11.x);
            const f16x2 e00 = u2h(c00.y), e01 = u2h(c01.y);
            const f16x2 e10 = u2h(c10.y), e11 = u2h(c11.y);
            const f16x2 t0  = a00 + wxh * (a01 - a00);   // v_pk_fma_f16
            const f16x2 b0v = a10 + wxh * (a11 - a10);
            const f16x2 t1  = e00 + wxh * (e01 - e00);
            const f16x2 b1v = e10 + wxh * (e11 - e10);
            const f16x2 v0  = t0 + wyh * (b0v - t0);
            const f16x2 v1  = t1 + wyh * (b1v - t1);
            const float s0 = (float)v0.x, s1 = (float)v0.y;
            const float s2 = (float)v1.x, s3 = (float)v1.y;
            if (s < 8) { tac[0]+=s0; tac[1]+=s1; tac[2]+=s2; tac[3]+=s3; }
            else       { nac[0]+=s0; nac[1]+=s1; nac[2]+=s2; nac[3]+=s3; }
        }
        const int c = 4 * cp;
        #pragma unroll
        for (int q = 0; q < 4; q++) {
            const float tq = tac[q] * (1.f / 9.f);
            const float nq = nac[q] * (1.f / 9.f);
            #pragma unroll
            for (int h = 0; h < HID; h++) {
                float a = hid[h];
                a = fmaf(wr[h * 128 + c + q],      tq, a);   // uniform s_load
                a = fmaf(wr[h * 128 + 64 + c + q], nq, a);
                hid[h] = a;
            }
        }
    }

    #pragma unroll
    for (int h = 0; h < HID; h++) hid[h] = fmaxf(hid[h], 0.f);

    // Epilogue: w = sigmoid(we @ hidden + be); out = (w[c] + w[c+64]) * x[c]
    const int pix = yy * Ww + xx;
    for (int c = 0; c < Cc; c++) {
        float z1 = be[c];
        float z2 = be[c + 64];
        #pragma unroll
        for (int h = 0; h < HID; h++) {
            z1 = fmaf(we[c * 8 + h],        hid[h], z1);
            z2 = fmaf(we[(c + 64) * 8 + h], hid[h], z2);
        }
        const float a1 = 1.f / (1.f + __expf(-z1));
        const float a2 = 1.f / (1.f + __expf(-z2));
        const float xv = xb[c * PLANE + pix];
        out[(size_t)(b * Cc + c) * PLANE + pix] = (a1 + a2) * xv;
    }
}

extern "C" void kernel_launch(void* const* d_in, const int* in_sizes, int n_in,
                              void* d_out, int out_size, void* d_ws, size_t ws_size,
                              hipStream_t stream) {
    const float* x  = (const float*)d_in[0];
    const float* w3 = (const float*)d_in[1];
    const float* b3 = (const float*)d_in[2];
    const float* w1 = (const float*)d_in[3];
    const float* b1 = (const float*)d_in[4];
    const float* wr = (const float*)d_in[5];
    const float* br = (const float*)d_in[6];
    const float* we = (const float*)d_in[7];
    const float* be = (const float*)d_in[8];
    float* out = (float*)d_out;

    dim3 grid(Ww / 64, Hh / 4, Bb);
    dim3 block(256);
    fused_kernel<<<grid, block, 0, stream>>>(x, w3, b3, w1, b1,
                                             wr, br, we, be, out);
}

// Round 5
// 477.217 us; speedup vs baseline: 1.4354x; 1.0461x over previous
//
#include <hip/hip_runtime.h>
#include <math.h>

#define Bb 8
#define Cc 64
#define Hh 256
#define Ww 256
#define HID 8
#define PLANE (Hh*Ww)

typedef _Float16 f16x2 __attribute__((ext_vector_type(2)));

static __device__ __forceinline__ f16x2 u2h(unsigned int u) {
    return __builtin_bit_cast(f16x2, u);
}
static __device__ __forceinline__ unsigned int pkrtz(float a, float b) {
    return __builtin_bit_cast(unsigned int, __builtin_amdgcn_cvt_pkrtz(a, b));
}

// ===== Fused kernel: theta (3x3 conv -> 1x1 -> sigmoid*pi) + oriented =====
// pooling + attention, one dispatch.
//
// Round-4 post-mortem: (256,4) made the backend spill the laundered
// descriptor set (VGPR_Count=64, WRITE_SIZE +40MB of scratch). Back to
// (256,3) -- the proven no-spill regime (r3: 84 VGPR, zero scratch).
//
// Staging is now single-barrier DOUBLE-BUFFERED: 32 unified stages
// (16 conv + 16 pool, 4 channels each, fp16-packed uint2 tiles of
// 13x74). Per stage: write buf[(g+1)&1] from prefetched regs, issue
// stage g+2 global loads, compute stage g from buf[g&1], one barrier.
// Hazard check: write buf[p^1] at stage g vs reads of buf[p^1] at stage
// g-1 are separated by stage g-1's barrier; reads at g+1 are after stage
// g's barrier. Barriers: 64 -> 33.
#define TPH 13
#define TPW 74
#define TPP 75          // uint2 row stride
#define TPN (TPH*TPW)   // 962

__global__ __launch_bounds__(256, 3) void fused_kernel(
    const float* __restrict__ x,
    const float* __restrict__ w3, const float* __restrict__ b3,
    const float* __restrict__ w1, const float* __restrict__ b1,
    const float* __restrict__ wr, const float* __restrict__ br,
    const float* __restrict__ we, const float* __restrict__ be,
    float* __restrict__ out)
{
    __shared__ uint2 buf[2][TPH * TPP];
    const int tid = threadIdx.x;
    const int tx = tid & 63;
    const int ty = tid >> 6;
    const int xx = blockIdx.x * 64 + tx;
    const int yy = blockIdx.y * 4 + ty;
    const int b  = blockIdx.z;
    const int row0 = blockIdx.y * 4 - 4;
    const int col0 = blockIdx.x * 64 - 4;

    // channel-invariant staging descriptors (4 positions per thread;
    // tail threads duplicate the last element -- benign same-value write)
    int goff[4], loff[4];
    #pragma unroll
    for (int k = 0; k < 4; k++) {
        int i = tid + k * 256;
        i = (i < TPN) ? i : (TPN - 1);
        const int r  = i / TPW;
        const int cc = i - r * TPW;
        const int gy = min(max(row0 + r, 0), Hh - 1);
        const int gx = min(max(col0 + cc, 0), Ww - 1);
        goff[k] = gy * Ww + gx;
        loff[k] = r * TPP + cc;
    }
    #pragma unroll
    for (int k = 0; k < 4; k++)
        asm volatile("" : "+v"(goff[k]), "+v"(loff[k]));

    const int lcen = (ty + 4) * TPP + (tx + 4);
    const float* xb = x + (size_t)b * Cc * PLANE;
    const bool interior = (blockIdx.y > 0) && (blockIdx.y < (Hh/4 - 1)) &&
                          (blockIdx.x > 0) && (blockIdx.x < (Ww/64 - 1));

    // ---- prologue: stage 0 -> buf[0]; stage 1 loads in flight ----
    float rvf[4][4];
    #pragma unroll
    for (int k = 0; k < 4; k++)
        #pragma unroll
        for (int q = 0; q < 4; q++)
            rvf[k][q] = xb[goff[k] + (size_t)q * PLANE];
    #pragma unroll
    for (int k = 0; k < 4; k++)
        buf[0][loff[k]] = make_uint2(pkrtz(rvf[k][0], rvf[k][1]),
                                     pkrtz(rvf[k][2], rvf[k][3]));
    {
        const float* xn = xb + (size_t)4 * PLANE;       // stage 1: ch 4..7
        #pragma unroll
        for (int k = 0; k < 4; k++)
            #pragma unroll
            for (int q = 0; q < 4; q++)
                rvf[k][q] = xn[goff[k] + (size_t)q * PLANE];
    }
    __syncthreads();

    // ================= pass 1: 3x3 conv accumulation (f32) =================
    float acc[HID];
    #pragma unroll
    for (int h = 0; h < HID; h++) acc[h] = 0.f;

    for (int g = 0; g < 16; g++) {
        const int pr = g & 1, nx = pr ^ 1;
        // write stage g+1 tile (regs already in flight; implicit waitcnt)
        #pragma unroll
        for (int k = 0; k < 4; k++)
            buf[nx][loff[k]] = make_uint2(pkrtz(rvf[k][0], rvf[k][1]),
                                          pkrtz(rvf[k][2], rvf[k][3]));
        {   // issue stage g+2 loads (g+2 in [2,17]; stage 16/17 = pool ch 0/4)
            const int s2 = g + 2;
            const int cb = (s2 < 16 ? s2 : s2 - 16) * 4;
            const float* xn = xb + (size_t)cb * PLANE;
            #pragma unroll
            for (int k = 0; k < 4; k++)
                #pragma unroll
                for (int q = 0; q < 4; q++)
                    rvf[k][q] = xn[goff[k] + (size_t)q * PLANE];
        }
        // compute conv on buf[pr], channels 4g..4g+3
        float va[9][4];
        #pragma unroll
        for (int dy = 0; dy < 3; dy++)
            #pragma unroll
            for (int dx = 0; dx < 3; dx++) {
                const uint2 cv = buf[pr][lcen + (dy - 1) * TPP + (dx - 1)];
                const f16x2 lo = u2h(cv.x), hi = u2h(cv.y);
                const int k = dy * 3 + dx;
                va[k][0] = (float)lo.x; va[k][1] = (float)lo.y;
                va[k][2] = (float)hi.x; va[k][3] = (float)hi.y;
            }
        if (!interior) {                      // zero-pad: clamp-tile * mask
            #pragma unroll
            for (int dy = 0; dy < 3; dy++)
                #pragma unroll
                for (int dx = 0; dx < 3; dx++) {
                    const int gy = yy + dy - 1, gx = xx + dx - 1;
                    const float m = (gy >= 0 && gy < Hh &&
                                     gx >= 0 && gx < Ww) ? 1.f : 0.f;
                    #pragma unroll
                    for (int q = 0; q < 4; q++) va[dy*3+dx][q] *= m;
                }
        }
        #pragma unroll
        for (int h = 0; h < HID; h++) {
            const float* wk = w3 + (size_t)(h * Cc + g * 4) * 9;  // uniform
            float a = acc[h];
            #pragma unroll
            for (int q = 0; q < 4; q++)
                #pragma unroll
                for (int k = 0; k < 9; k++)
                    a = fmaf(wk[q * 9 + k], va[k][q], a);
            acc[h] = a;
        }
        __syncthreads();
    }

    // ================= theta -> bilinear descriptors =================
    float z = b1[0];
    #pragma unroll
    for (int h = 0; h < HID; h++) {
        float hr = acc[h] + b3[h];
        hr = hr > 0.f ? hr : 0.f;
        z = fmaf(w1[h], hr, z);
    }
    const float theta = 3.14159265358979f / (1.f + __expf(-z));
    float vy, vx;
    __sincosf(theta, &vy, &vx);               // vy=sin, vx=cos

    // 16 samples (8 tan + 8 nor, t != 0; t=0 is exactly the center pixel).
    // Clamp trick: x0=min(floor(cx),W-2), wx=cx-x0 matches reference edges.
    // Lerp weights stored as broadcast half2 for packed-fp16 bilinear.
    int off[16];
    unsigned int wxp[16], wyp[16];
    #pragma unroll
    for (int s = 0; s < 9; s++) {
        if (s == 4) continue;
        const int j = (s < 4) ? s : s - 1;    // 0..7
        const float t = (float)(s - 4);
        {   // tangential: cy = y + t*sin, cx = x + t*cos
            float cy = fminf(fmaxf((float)yy + t * vy, 0.f), (float)(Hh - 1));
            float cx = fminf(fmaxf((float)xx + t * vx, 0.f), (float)(Ww - 1));
            int y0 = min((int)cy, Hh - 2);
            int x0 = min((int)cx, Ww - 2);
            off[j] = (y0 - row0) * TPP + (x0 - col0);
            const float wy = cy - (float)y0, wxx = cx - (float)x0;
            wxp[j] = pkrtz(wxx, wxx);
            wyp[j] = pkrtz(wy,  wy);
        }
        {   // normal: cy = y + t*cos, cx = x - t*sin
            float cy = fminf(fmaxf((float)yy + t * vx, 0.f), (float)(Hh - 1));
            float cx = fminf(fmaxf((float)xx - t * vy, 0.f), (float)(Ww - 1));
            int y0 = min((int)cy, Hh - 2);
            int x0 = min((int)cx, Ww - 2);
            off[8 + j] = (y0 - row0) * TPP + (x0 - col0);
            const float wy = cy - (float)y0, wxx = cx - (float)x0;
            wxp[8 + j] = pkrtz(wxx, wxx);
            wyp[8 + j] = pkrtz(wy,  wy);
        }
    }
    // Force residency: opaque defs cannot be rematerialized per stage.
    #pragma unroll
    for (int s = 0; s < 16; s++)
        asm volatile("" : "+v"(off[s]), "+v"(wxp[s]), "+v"(wyp[s]));

    // ================= pass 2: oriented pooling =================
    float hid[HID];
    #pragma unroll
    for (int h = 0; h < HID; h++) hid[h] = br[h];

    for (int g = 16; g < 32; g++) {
        const int pr = g & 1, nx = pr ^ 1;
        if (g < 31) {
            #pragma unroll
            for (int k = 0; k < 4; k++)
                buf[nx][loff[k]] = make_uint2(pkrtz(rvf[k][0], rvf[k][1]),
                                              pkrtz(rvf[k][2], rvf[k][3]));
            if (g < 30) {                     // issue stage g+2 loads
                const int cb = (g + 2 - 16) * 4;
                const float* xn = xb + (size_t)cb * PLANE;
                #pragma unroll
                for (int k = 0; k < 4; k++)
                    #pragma unroll
                    for (int q = 0; q < 4; q++)
                        rvf[k][q] = xn[goff[k] + (size_t)q * PLANE];
            }
        }

        const uint2 cc = buf[pr][lcen];       // exact t=0 sample, both dirs
        const f16x2 clo = u2h(cc.x), chi = u2h(cc.y);
        float tac[4], nac[4];
        tac[0] = nac[0] = (float)clo.x;
        tac[1] = nac[1] = (float)clo.y;
        tac[2] = nac[2] = (float)chi.x;
        tac[3] = nac[3] = (float)chi.y;

        #pragma unroll
        for (int s = 0; s < 16; s++) {
            const int o = off[s];
            const uint2 c00 = buf[pr][o];
            const uint2 c01 = buf[pr][o + 1];        // ds_read2_b64 pair
            const uint2 c10 = buf[pr][o + TPP];
            const uint2 c11 = buf[pr][o + TPP + 1];  // ds_read2_b64 pair
            const f16x2 wxh = u2h(wxp[s]);
            const f16x2 wyh = u2h(wyp[s]);
            const f16x2 a00 = u2h(c00.x), a01 = u2h(c01.x);
            const f16x2 a10 = u2h(c10.x), a11 = u2h(c11.x);
            const f16x2 e00 = u2h(c00.y), e01 = u2h(c01.y);
            const f16x2 e10 = u2h(c10.y), e11 = u2h(c11.y);
            const f16x2 t0  = a00 + wxh * (a01 - a00);   // v_pk_fma_f16
            const f16x2 b0v = a10 + wxh * (a11 - a10);
            const f16x2 t1  = e00 + wxh * (e01 - e00);
            const f16x2 b1v = e10 + wxh * (e11 - e10);
            const f16x2 v0  = t0 + wyh * (b0v - t0);
            const f16x2 v1  = t1 + wyh * (b1v - t1);
            const float s0 = (float)v0.x, s1 = (float)v0.y;
            const float s2 = (float)v1.x, s3 = (float)v1.y;
            if (s < 8) { tac[0]+=s0; tac[1]+=s1; tac[2]+=s2; tac[3]+=s3; }
            else       { nac[0]+=s0; nac[1]+=s1; nac[2]+=s2; nac[3]+=s3; }
        }
        const int c = 4 * (g - 16);
        #pragma unroll
        for (int q = 0; q < 4; q++) {
            const float tq = tac[q] * (1.f / 9.f);
            const float nq = nac[q] * (1.f / 9.f);
            #pragma unroll
            for (int h = 0; h < HID; h++) {
                float a = hid[h];
                a = fmaf(wr[h * 128 + c + q],      tq, a);   // uniform s_load
                a = fmaf(wr[h * 128 + 64 + c + q], nq, a);
                hid[h] = a;
            }
        }
        if (g < 31) __syncthreads();
    }

    #pragma unroll
    for (int h = 0; h < HID; h++) hid[h] = fmaxf(hid[h], 0.f);

    // Epilogue: w = sigmoid(we @ hidden + be); out = (w[c] + w[c+64]) * x[c]
    const int pix = yy * Ww + xx;
    for (int c = 0; c < Cc; c++) {
        float z1 = be[c];
        float z2 = be[c + 64];
        #pragma unroll
        for (int h = 0; h < HID; h++) {
            z1 = fmaf(we[c * 8 + h],        hid[h], z1);
            z2 = fmaf(we[(c + 64) * 8 + h], hid[h], z2);
        }
        const float a1 = 1.f / (1.f + __expf(-z1));
        const float a2 = 1.f / (1.f + __expf(-z2));
        const float xv = xb[c * PLANE + pix];
        out[(size_t)(b * Cc + c) * PLANE + pix] = (a1 + a2) * xv;
    }
}

extern "C" void kernel_launch(void* const* d_in, const int* in_sizes, int n_in,
                              void* d_out, int out_size, void* d_ws, size_t ws_size,
                              hipStream_t stream) {
    const float* x  = (const float*)d_in[0];
    const float* w3 = (const float*)d_in[1];
    const float* b3 = (const float*)d_in[2];
    const float* w1 = (const float*)d_in[3];
    const float* b1 = (const float*)d_in[4];
    const float* wr = (const float*)d_in[5];
    const float* br = (const float*)d_in[6];
    const float* we = (const float*)d_in[7];
    const float* be = (const float*)d_in[8];
    float* out = (float*)d_out;

    dim3 grid(Ww / 64, Hh / 4, Bb);
    dim3 block(256);
    fused_kernel<<<grid, block, 0, stream>>>(x, w3, b3, w1, b1,
                                             wr, br, we, be, out);
}